// Round 3
// baseline (2942.662 us; speedup 1.0000x reference)
//
#include <hip/hip_runtime.h>
#include <hip/hip_bf16.h>

typedef unsigned short u16;
typedef __attribute__((ext_vector_type(8))) short short8;
typedef __attribute__((ext_vector_type(8))) __bf16 bf16x8;
typedef __attribute__((ext_vector_type(4))) float f32x4;
typedef __attribute__((ext_vector_type(4))) unsigned int u32x4;

#define BB 4096
#define TT 19
#define INP 17
#define HH 1024

__device__ __forceinline__ u16 f2bfu(float f) {
    __hip_bfloat16 b = __float2bfloat16(f);
    return __builtin_bit_cast(unsigned short, b);
}
__device__ __forceinline__ float bfu2f(u16 u) {
    unsigned int x = ((unsigned int)u) << 16;
    return __builtin_bit_cast(float, x);
}
__device__ __forceinline__ float fast_sigmoid(float x) {
    return 1.f / (1.f + __expf(-x));
}
__device__ __forceinline__ float fast_tanh(float x) {
    float e = __expf(2.f * x);
    return (e - 1.f) / (e + 1.f);
}

// LDS tile: [rows][32] bf16 (u16), 16B-slot XOR swizzle for bank-conflict-free
// ds_read_b128 fragment reads (lanes stride rows). Returns u16-element offset.
__device__ __forceinline__ int lds_off(int row, int s) {
    return row * 32 + (((s ^ (row ^ (row >> 2))) & 3) * 8);
}

// ---------------- prep kernels ----------------
__global__ void prep_w(const float* __restrict__ W, u16* __restrict__ whi, u16* __restrict__ wlo) {
    int idx = (blockIdx.x * 256 + threadIdx.x) * 8;
#pragma unroll
    for (int e = 0; e < 8; ++e) {
        float v = W[idx + e];
        u16 h = f2bfu(v);
        whi[idx + e] = h;
        wlo[idx + e] = f2bfu(v - bfu2f(h));
    }
}

__global__ void prep_misc(const float* __restrict__ Wih, const float* __restrict__ bih,
                          const float* __restrict__ bhh, u16* __restrict__ wihp,
                          float* __restrict__ bias) {
    int idx = blockIdx.x * 256 + threadIdx.x;  // 0 .. 131071
    int r = idx >> 5, c = idx & 31;
    wihp[idx] = (c < INP) ? f2bfu(Wih[r * INP + c]) : (u16)0;
    if (idx < 4 * HH) bias[idx] = bih[idx] + bhh[idx];
}

__global__ void prep_x(const float* __restrict__ x, u16* __restrict__ xpad) {
    int idx = blockIdx.x * 256 + threadIdx.x;  // 0 .. 19*4096*32-1
    int c = idx & 31;
    int rb = idx >> 5;       // t*4096 + b
    int t = rb >> 12;
    int b = rb & 4095;
    xpad[idx] = (c < INP) ? f2bfu(x[((size_t)b * TT + t) * INP + c]) : (u16)0;
}

// ---------------- fused gates + cell kernel ----------------
// grid: dim3(64, 16)  (x = m-tile, y = n-tile), 256 threads (4 waves).
// Block computes gates[m0..m0+64][4 gates x 64 cols], applies LSTM cell,
// writes h (bf16) and c (fp32, in d_out c_fin region).
__global__ __launch_bounds__(256, 4) void lstm_gates(
    const u16* __restrict__ h_in, u16* __restrict__ h_out,
    float* __restrict__ c_buf, const u16* __restrict__ whi,
    const u16* __restrict__ wlo, const u16* __restrict__ wihp,
    const float* __restrict__ bias, const u16* __restrict__ xpad,
    float* __restrict__ h_fin, int t, int is_last)
{
    __shared__ u16 sA[64 * 32];
    __shared__ u16 sB0[256 * 32];
    __shared__ u16 sB1[256 * 32];

    const int tid = threadIdx.x;
    const int lane = tid & 63;
    const int wv = tid >> 6;
    const int mt = blockIdx.x;   // 0..63
    const int nt = blockIdx.y;   // 0..15
    const int m0 = mt * 64;
    const int r16 = lane & 15;
    const int s4 = lane >> 4;

    // staging mapping: thread -> (row, 16B chunk)
    const int srow = tid >> 2;   // 0..63
    const int sq = tid & 3;
    const int a_dst = lds_off(srow, sq);

    f32x4 acc[4][4];
#pragma unroll
    for (int mf = 0; mf < 4; ++mf)
#pragma unroll
        for (int g = 0; g < 4; ++g) acc[mf][g] = (f32x4){0.f, 0.f, 0.f, 0.f};

    int aoff[4], boff[4];
#pragma unroll
    for (int mf = 0; mf < 4; ++mf) aoff[mf] = lds_off(mf * 16 + r16, s4);
#pragma unroll
    for (int g = 0; g < 4; ++g) boff[g] = lds_off(g * 64 + wv * 16 + r16, s4);

    // ---- x chunk (K = 0..31 padded from 17) ----
    {
        const u16* xsrc = xpad + ((size_t)t * BB + m0 + srow) * 32 + sq * 8;
        *(u32x4*)&sA[a_dst] = *(const u32x4*)xsrc;
#pragma unroll
        for (int rep = 0; rep < 4; ++rep) {
            int r = rep * 64 + srow;
            int wrow = (r >> 6) * HH + nt * 64 + (r & 63);
            *(u32x4*)&sB0[lds_off(r, sq)] = *(const u32x4*)(wihp + wrow * 32 + sq * 8);
        }
    }
    __syncthreads();
    {
        bf16x8 af[4];
#pragma unroll
        for (int mf = 0; mf < 4; ++mf)
            af[mf] = __builtin_bit_cast(bf16x8, *(const short8*)&sA[aoff[mf]]);
#pragma unroll
        for (int g = 0; g < 4; ++g) {
            bf16x8 bh = __builtin_bit_cast(bf16x8, *(const short8*)&sB0[boff[g]]);
#pragma unroll
            for (int mf = 0; mf < 4; ++mf)
                acc[mf][g] = __builtin_amdgcn_mfma_f32_16x16x32_bf16(af[mf], bh, acc[mf][g], 0, 0, 0);
        }
    }

    // ---- h chunks: K = 1024, chunk 32, two passes (W hi + lo) ----
    for (int kc = 0; kc < HH; kc += 32) {
        __syncthreads();
        *(u32x4*)&sA[a_dst] = *(const u32x4*)(h_in + (m0 + srow) * HH + kc + sq * 8);
#pragma unroll
        for (int rep = 0; rep < 4; ++rep) {
            int r = rep * 64 + srow;
            int wrow = (r >> 6) * HH + nt * 64 + (r & 63);
            int dst = lds_off(r, sq);
            *(u32x4*)&sB0[dst] = *(const u32x4*)(whi + (size_t)wrow * HH + kc + sq * 8);
            *(u32x4*)&sB1[dst] = *(const u32x4*)(wlo + (size_t)wrow * HH + kc + sq * 8);
        }
        __syncthreads();

        bf16x8 af[4];
#pragma unroll
        for (int mf = 0; mf < 4; ++mf)
            af[mf] = __builtin_bit_cast(bf16x8, *(const short8*)&sA[aoff[mf]]);
#pragma unroll
        for (int g = 0; g < 4; ++g) {
            bf16x8 bh = __builtin_bit_cast(bf16x8, *(const short8*)&sB0[boff[g]]);
            bf16x8 bl = __builtin_bit_cast(bf16x8, *(const short8*)&sB1[boff[g]]);
#pragma unroll
            for (int mf = 0; mf < 4; ++mf) {
                acc[mf][g] = __builtin_amdgcn_mfma_f32_16x16x32_bf16(af[mf], bh, acc[mf][g], 0, 0, 0);
                acc[mf][g] = __builtin_amdgcn_mfma_f32_16x16x32_bf16(af[mf], bl, acc[mf][g], 0, 0, 0);
            }
        }
    }

    // ---- epilogue: LSTM cell ----
    const int n = nt * 64 + wv * 16 + r16;
    const float bi = bias[n];
    const float bf_ = bias[HH + n];
    const float bg = bias[2 * HH + n];
    const float bo = bias[3 * HH + n];
#pragma unroll
    for (int mf = 0; mf < 4; ++mf) {
#pragma unroll
        for (int j = 0; j < 4; ++j) {
            int brow = m0 + mf * 16 + s4 * 4 + j;
            float iv = fast_sigmoid(acc[mf][0][j] + bi);
            float fv = fast_sigmoid(acc[mf][1][j] + bf_);
            float gv = fast_tanh(acc[mf][2][j] + bg);
            float ov = fast_sigmoid(acc[mf][3][j] + bo);
            size_t ci = (size_t)brow * HH + n;
            float cold = c_buf[ci];
            float cnew = fv * cold + iv * gv;
            float hnew = ov * fast_tanh(cnew);
            c_buf[ci] = cnew;
            h_out[ci] = f2bfu(hnew);
            if (is_last) h_fin[ci] = hnew;
        }
    }
}

// ---------------- output projection ----------------
// out[b, t, i] = sum_k h[b,k] * W_lin[i,k] + b_lin[i]
// W_lin staged in LDS as bf16 (34,816 B — fits static LDS limit).
__global__ __launch_bounds__(256) void lstm_proj(
    const u16* __restrict__ h_bf, const float* __restrict__ Wlin,
    const float* __restrict__ blin, float* __restrict__ outp, int t)
{
    __shared__ u16 sW[INP * HH];
    const int tid = threadIdx.x;
    for (int i = tid * 2; i < INP * HH; i += 512) {
        unsigned int lo = f2bfu(Wlin[i]);
        unsigned int hi = f2bfu(Wlin[i + 1]);
        *(unsigned int*)&sW[i] = lo | (hi << 16);
    }
    __syncthreads();

    const int lane = tid & 63;
    const int wv = tid >> 6;
    const int b0 = blockIdx.x * 32 + wv * 8;
    for (int r = 0; r < 8; ++r) {
        int b = b0 + r;
        float part[INP];
#pragma unroll
        for (int i = 0; i < INP; ++i) part[i] = 0.f;
#pragma unroll
        for (int j = 0; j < 8; ++j) {
            int k = 2 * lane + 128 * j;
            unsigned int hp = *(const unsigned int*)&h_bf[(size_t)b * HH + k];
            float h0 = bfu2f((u16)hp);
            float h1 = bfu2f((u16)(hp >> 16));
#pragma unroll
            for (int i = 0; i < INP; ++i) {
                unsigned int wp = *(const unsigned int*)&sW[i * HH + k];
                part[i] += h0 * bfu2f((u16)wp) + h1 * bfu2f((u16)(wp >> 16));
            }
        }
#pragma unroll
        for (int i = 0; i < INP; ++i) {
            float v = part[i];
            v += __shfl_down(v, 32);
            v += __shfl_down(v, 16);
            v += __shfl_down(v, 8);
            v += __shfl_down(v, 4);
            v += __shfl_down(v, 2);
            v += __shfl_down(v, 1);
            if (lane == 0) outp[((size_t)b * TT + t) * INP + i] = v + blin[i];
        }
    }
}

// ---------------- launch ----------------
extern "C" void kernel_launch(void* const* d_in, const int* in_sizes, int n_in,
                              void* d_out, int out_size, void* d_ws, size_t ws_size,
                              hipStream_t stream)
{
    const float* x    = (const float*)d_in[0];
    const float* Wih  = (const float*)d_in[1];
    const float* Whh  = (const float*)d_in[2];
    const float* bih  = (const float*)d_in[3];
    const float* bhh  = (const float*)d_in[4];
    const float* Wlin = (const float*)d_in[5];
    const float* blin = (const float*)d_in[6];
    float* out = (float*)d_out;

    char* ws = (char*)d_ws;
    u16* hb0   = (u16*)(ws);                          //  8,388,608 B
    u16* hb1   = (u16*)(ws + 8388608);                //  8,388,608 B
    u16* xpad  = (u16*)(ws + 16777216);               //  4,980,736 B
    u16* whi   = (u16*)(ws + 21757952);               //  8,388,608 B
    u16* wlo   = (u16*)(ws + 30146560);               //  8,388,608 B
    u16* wihp  = (u16*)(ws + 38535168);               //    262,144 B
    float* bias = (float*)(ws + 38797312);            //     16,384 B

    float* h_fin = out + (size_t)BB * TT * INP;       // h_fin region
    float* c_buf = h_fin + (size_t)BB * HH;           // c_fin region doubles as c state

    hipMemsetAsync(hb0, 0, (size_t)BB * HH * sizeof(u16), stream);
    hipMemsetAsync(c_buf, 0, (size_t)BB * HH * sizeof(float), stream);
    prep_w<<<2048, 256, 0, stream>>>(Whh, whi, wlo);
    prep_misc<<<512, 256, 0, stream>>>(Wih, bih, bhh, wihp, bias);
    prep_x<<<9728, 256, 0, stream>>>(x, xpad);

    for (int t = 0; t < TT; ++t) {
        const u16* hin = (t & 1) ? hb1 : hb0;
        u16* hout = (t & 1) ? hb0 : hb1;
        lstm_gates<<<dim3(64, 16), 256, 0, stream>>>(
            hin, hout, c_buf, whi, wlo, wihp, bias, xpad, h_fin, t, (t == TT - 1) ? 1 : 0);
        lstm_proj<<<128, 256, 0, stream>>>(hout, Wlin, blin, out, t);
    }
}

// Round 5
// 2697.348 us; speedup vs baseline: 1.0909x; 1.0909x over previous
//
#include <hip/hip_runtime.h>
#include <hip/hip_bf16.h>

typedef unsigned short u16;
typedef __attribute__((ext_vector_type(8))) short short8;
typedef __attribute__((ext_vector_type(8))) __bf16 bf16x8;
typedef __attribute__((ext_vector_type(4))) float f32x4;
typedef __attribute__((ext_vector_type(4))) unsigned int u32x4;

#define BB 4096
#define TT 19
#define INP 17
#define HH 1024

__device__ __forceinline__ u16 f2bfu(float f) {
    __hip_bfloat16 b = __float2bfloat16(f);
    return __builtin_bit_cast(unsigned short, b);
}
__device__ __forceinline__ float bfu2f(u16 u) {
    unsigned int x = ((unsigned int)u) << 16;
    return __builtin_bit_cast(float, x);
}
__device__ __forceinline__ float fast_sigmoid(float x) {
    return 1.f / (1.f + __expf(-x));
}
__device__ __forceinline__ float fast_tanh(float x) {
    float e = __expf(2.f * x);
    return (e - 1.f) / (e + 1.f);
}

// async 16B global -> LDS (linear dest: wave-uniform base + lane*16)
__device__ __forceinline__ void cp16(void* l, const void* g) {
    __builtin_amdgcn_global_load_lds(
        (const __attribute__((address_space(1))) unsigned int*)g,
        (__attribute__((address_space(3))) unsigned int*)l, 16, 0, 0);
}

// LDS tile logical layout [rows][32] bf16; 16B-slot XOR swizzle applied on the
// READ side and on the GLOBAL SOURCE address (linear LDS dest for gload_lds).
// Swizzle is an involution: slot' = slot ^ f(row), f(row) = (row ^ row>>2) & 3.
__device__ __forceinline__ int lds_off(int row, int s) {
    return row * 32 + (((s ^ (row ^ (row >> 2))) & 3) * 8);
}

// ---------------- prep kernels ----------------
// grid MUST be 2048: 2048*256*8 == 4*HH*HH elements exactly.
__global__ void prep_w(const float* __restrict__ W, u16* __restrict__ whi) {
    int idx = (blockIdx.x * 256 + threadIdx.x) * 8;
#pragma unroll
    for (int e = 0; e < 8; ++e) whi[idx + e] = f2bfu(W[idx + e]);
}

__global__ void prep_misc(const float* __restrict__ Wih, const float* __restrict__ bih,
                          const float* __restrict__ bhh, const float* __restrict__ Wlin,
                          u16* __restrict__ wihp, float* __restrict__ bias,
                          u16* __restrict__ wlinp) {
    int idx = blockIdx.x * 256 + threadIdx.x;  // 0 .. 131071
    int r = idx >> 5, c = idx & 31;
    wihp[idx] = (c < INP) ? f2bfu(Wih[r * INP + c]) : (u16)0;
    if (idx < 4 * HH) bias[idx] = bih[idx] + bhh[idx];
    if (idx < INP * HH) wlinp[idx] = f2bfu(Wlin[idx]);
}

__global__ void prep_x(const float* __restrict__ x, u16* __restrict__ xpad) {
    int idx = blockIdx.x * 256 + threadIdx.x;  // 0 .. 19*4096*32-1
    int c = idx & 31;
    int rb = idx >> 5;       // t*4096 + b
    int t = rb >> 12;
    int b = rb & 4095;
    xpad[idx] = (c < INP) ? f2bfu(x[((size_t)b * TT + t) * INP + c]) : (u16)0;
}

// ---------------- fused gates + cell + projection kernel ----------------
// grid dim3(64,16): x = m-tile (64 batch rows), y = nt (64 h-cols). 256 thr.
// gates GEMM (single-pass bf16 W) -> LSTM cell -> h/c writes -> partial
// projection (this block's 64 cols) accumulated into out via atomicAdd.
__global__ __launch_bounds__(256, 8) void lstm_gates(
    const u16* __restrict__ h_in, u16* __restrict__ h_out,
    float* __restrict__ c_buf, const u16* __restrict__ whi,
    const u16* __restrict__ wihp, const float* __restrict__ bias,
    const u16* __restrict__ xpad, const u16* __restrict__ wlinp,
    const float* __restrict__ blin, float* __restrict__ outp,
    float* __restrict__ h_fin, int t, int is_last)
{
    __shared__ u16 sA[64 * 32];      //  4 KB  A tile (h rows)
    __shared__ u16 sB0[256 * 32];    // 16 KB  B tile (W rows); reused as h-tile
    __shared__ u16 sWl[INP * 64];    // 2.125 KB  W_lin slice [17][64]

    const int tid = threadIdx.x;
    const int lane = tid & 63;
    const int wv = tid >> 6;
    const int m0 = blockIdx.x * 64;
    const int nt = blockIdx.y;
    const int r16 = lane & 15;
    const int s4 = lane >> 4;

    // staging mapping: thread -> (row srow, 16B slot sq); linear LDS dest,
    // swizzled global source slot xo = (sq ^ f(srow)) * 8 elems.
    const int srow = tid >> 2;
    const int sq = tid & 3;
    const int xo = ((sq ^ (srow ^ (srow >> 2))) & 3) * 8;

    // stage W_lin slice for this nt (once)
    for (int k = tid; k < INP * 64; k += 256)
        sWl[k] = wlinp[(k >> 6) * HH + nt * 64 + (k & 63)];

    f32x4 acc[4][4];
#pragma unroll
    for (int mf = 0; mf < 4; ++mf)
#pragma unroll
        for (int g = 0; g < 4; ++g) acc[mf][g] = (f32x4){0.f, 0.f, 0.f, 0.f};

    int aoff[4], boff[4];
#pragma unroll
    for (int mf = 0; mf < 4; ++mf) aoff[mf] = lds_off(mf * 16 + r16, s4);
#pragma unroll
    for (int g = 0; g < 4; ++g) boff[g] = lds_off(g * 64 + wv * 16 + r16, s4);

    // ---- x chunk (K padded 17 -> 32) ----
    cp16(&sA[tid * 8], xpad + ((size_t)t * BB + m0 + srow) * 32 + xo);
#pragma unroll
    for (int rep = 0; rep < 4; ++rep)
        cp16(&sB0[rep * 2048 + tid * 8],
             wihp + (size_t)(rep * HH + nt * 64 + srow) * 32 + xo);
    __syncthreads();
    {
        bf16x8 af[4];
#pragma unroll
        for (int mf = 0; mf < 4; ++mf)
            af[mf] = __builtin_bit_cast(bf16x8, *(const short8*)&sA[aoff[mf]]);
#pragma unroll
        for (int g = 0; g < 4; ++g) {
            bf16x8 bh = __builtin_bit_cast(bf16x8, *(const short8*)&sB0[boff[g]]);
#pragma unroll
            for (int mf = 0; mf < 4; ++mf)
                acc[mf][g] = __builtin_amdgcn_mfma_f32_16x16x32_bf16(af[mf], bh, acc[mf][g], 0, 0, 0);
        }
    }

    // ---- h chunks: K = 1024, BK = 32, single bf16 pass ----
    for (int kc = 0; kc < HH; kc += 32) {
        __syncthreads();   // all waves done reading previous tiles
        cp16(&sA[tid * 8], h_in + (size_t)(m0 + srow) * HH + kc + xo);
#pragma unroll
        for (int rep = 0; rep < 4; ++rep)
            cp16(&sB0[rep * 2048 + tid * 8],
                 whi + (size_t)(rep * HH + nt * 64 + srow) * HH + kc + xo);
        __syncthreads();   // drains vmcnt -> tiles resident

        bf16x8 af[4];
#pragma unroll
        for (int mf = 0; mf < 4; ++mf)
            af[mf] = __builtin_bit_cast(bf16x8, *(const short8*)&sA[aoff[mf]]);
#pragma unroll
        for (int g = 0; g < 4; ++g) {
            bf16x8 bh = __builtin_bit_cast(bf16x8, *(const short8*)&sB0[boff[g]]);
#pragma unroll
            for (int mf = 0; mf < 4; ++mf)
                acc[mf][g] = __builtin_amdgcn_mfma_f32_16x16x32_bf16(af[mf], bh, acc[mf][g], 0, 0, 0);
        }
    }

    // ---- epilogue: LSTM cell; stash h-tile in LDS for fused projection ----
    __syncthreads();                 // done reading sB0 as B tile
    u16* hT = sB0;                   // reuse: hT[c*64 + ((r + 2c) & 63)] = h[r][c]
    const int n = nt * 64 + wv * 16 + r16;
    const int nl = wv * 16 + r16;    // local col 0..63
    const float bi = bias[n];
    const float bf_ = bias[HH + n];
    const float bg = bias[2 * HH + n];
    const float bo = bias[3 * HH + n];
#pragma unroll
    for (int mf = 0; mf < 4; ++mf) {
#pragma unroll
        for (int j = 0; j < 4; ++j) {
            int rl = mf * 16 + s4 * 4 + j;         // local row 0..63
            int brow = m0 + rl;
            float iv = fast_sigmoid(acc[mf][0][j] + bi);
            float fv = fast_sigmoid(acc[mf][1][j] + bf_);
            float gv = fast_tanh(acc[mf][2][j] + bg);
            float ov = fast_sigmoid(acc[mf][3][j] + bo);
            size_t ci = (size_t)brow * HH + n;
            float cold = c_buf[ci];
            float cnew = fv * cold + iv * gv;
            float hnew = ov * fast_tanh(cnew);
            c_buf[ci] = cnew;
            u16 hb = f2bfu(hnew);
            h_out[ci] = hb;
            hT[nl * 64 + ((rl + 2 * nl) & 63)] = hb;
            if (is_last) h_fin[ci] = hnew;
        }
    }
    __syncthreads();

    // ---- fused projection partial: out[b,i] += sum_c h[b,c]*Wlin[i,c] ----
    // thread -> row r_local = tid&63; wave wv owns i in {wv, wv+4, ...}.
    {
        const int rl = tid & 63;
        float part[5] = {0.f, 0.f, 0.f, 0.f, 0.f};
        for (int c = 0; c < 64; ++c) {
            float hv = bfu2f(hT[c * 64 + ((rl + 2 * c) & 63)]);
#pragma unroll
            for (int k = 0; k < 5; ++k) {
                int i = wv + 4 * k;
                if (i < INP) part[k] += hv * bfu2f(sWl[i * 64 + c]);
            }
        }
        size_t ob = ((size_t)(m0 + rl) * TT + t) * INP;
#pragma unroll
        for (int k = 0; k < 5; ++k) {
            int i = wv + 4 * k;
            if (i < INP) {
                float v = part[k];
                if (nt == 0) v += blin[i];   // bias added exactly once
                atomicAdd(&outp[ob + i], v);
            }
        }
    }
}

// ---------------- launch ----------------
extern "C" void kernel_launch(void* const* d_in, const int* in_sizes, int n_in,
                              void* d_out, int out_size, void* d_ws, size_t ws_size,
                              hipStream_t stream)
{
    const float* x    = (const float*)d_in[0];
    const float* Wih  = (const float*)d_in[1];
    const float* Whh  = (const float*)d_in[2];
    const float* bih  = (const float*)d_in[3];
    const float* bhh  = (const float*)d_in[4];
    const float* Wlin = (const float*)d_in[5];
    const float* blin = (const float*)d_in[6];
    float* out = (float*)d_out;

    char* ws = (char*)d_ws;
    u16* hb0    = (u16*)(ws);                      //  8,388,608 B
    u16* hb1    = (u16*)(ws + 8388608);            //  8,388,608 B
    u16* xpad   = (u16*)(ws + 16777216);           //  4,980,736 B
    u16* whi    = (u16*)(ws + 21757952);           //  8,388,608 B
    u16* wihp   = (u16*)(ws + 30146560);           //    262,144 B
    u16* wlinp  = (u16*)(ws + 30408704);           //     34,816 B
    float* bias = (float*)(ws + 30443520);         //     16,384 B

    float* h_fin = out + (size_t)BB * TT * INP;    // h_fin region
    float* c_buf = h_fin + (size_t)BB * HH;        // c_fin region = c state

    hipMemsetAsync(out, 0, (size_t)BB * TT * INP * sizeof(float), stream);
    hipMemsetAsync(hb0, 0, (size_t)BB * HH * sizeof(u16), stream);
    hipMemsetAsync(c_buf, 0, (size_t)BB * HH * sizeof(float), stream);
    prep_w<<<2048, 256, 0, stream>>>(Whh, whi);
    prep_misc<<<512, 256, 0, stream>>>(Wih, bih, bhh, Wlin, wihp, bias, wlinp);
    prep_x<<<9728, 256, 0, stream>>>(x, xpad);

    for (int t = 0; t < TT; ++t) {
        const u16* hin = (t & 1) ? hb1 : hb0;
        u16* hout = (t & 1) ? hb0 : hb1;
        lstm_gates<<<dim3(64, 16), 256, 0, stream>>>(
            hin, hout, c_buf, whi, wihp, bias, xpad, wlinp, blin, out,
            h_fin, t, (t == TT - 1) ? 1 : 0);
    }
}

// Round 6
// 2542.568 us; speedup vs baseline: 1.1574x; 1.0609x over previous
//
#include <hip/hip_runtime.h>
#include <hip/hip_bf16.h>

typedef unsigned short u16;
typedef __attribute__((ext_vector_type(8))) short short8;
typedef __attribute__((ext_vector_type(8))) __bf16 bf16x8;
typedef __attribute__((ext_vector_type(4))) float f32x4;
typedef __attribute__((ext_vector_type(4))) unsigned int u32x4;

#define BB 4096
#define TT 19
#define INP 17
#define HH 1024

__device__ __forceinline__ u16 f2bfu(float f) {
    __hip_bfloat16 b = __float2bfloat16(f);
    return __builtin_bit_cast(unsigned short, b);
}
__device__ __forceinline__ float bfu2f(u16 u) {
    unsigned int x = ((unsigned int)u) << 16;
    return __builtin_bit_cast(float, x);
}
__device__ __forceinline__ float fast_sigmoid(float x) {
    return 1.f / (1.f + __expf(-x));
}
__device__ __forceinline__ float fast_tanh(float x) {
    float e = __expf(2.f * x);
    return (e - 1.f) / (e + 1.f);
}

// LDS tile: [rows][32] bf16 (u16), 16B-slot XOR swizzle (involution) applied
// on both ds_write and ds_read. Conflict-free for row-strided b128 frag reads.
__device__ __forceinline__ int lds_off(int row, int s) {
    return row * 32 + (((s ^ (row ^ (row >> 2))) & 3) * 8);
}

// ---------------- prep kernels ----------------
// grid MUST be 2048: 2048*256*8 == 4*HH*HH elements exactly.
__global__ void prep_w(const float* __restrict__ W, u16* __restrict__ whi) {
    int idx = (blockIdx.x * 256 + threadIdx.x) * 8;
#pragma unroll
    for (int e = 0; e < 8; ++e) whi[idx + e] = f2bfu(W[idx + e]);
}

__global__ void prep_misc(const float* __restrict__ Wih, const float* __restrict__ bih,
                          const float* __restrict__ bhh, const float* __restrict__ Wlin,
                          u16* __restrict__ wihp, float* __restrict__ bias,
                          u16* __restrict__ wlinp) {
    int idx = blockIdx.x * 256 + threadIdx.x;  // 0 .. 131071
    int r = idx >> 5, c = idx & 31;
    wihp[idx] = (c < INP) ? f2bfu(Wih[r * INP + c]) : (u16)0;
    if (idx < 4 * HH) bias[idx] = bih[idx] + bhh[idx];
    if (idx < INP * HH) wlinp[idx] = f2bfu(Wlin[idx]);
}

__global__ void prep_x(const float* __restrict__ x, u16* __restrict__ xpad) {
    int idx = blockIdx.x * 256 + threadIdx.x;  // 0 .. 19*4096*32-1
    int c = idx & 31;
    int rb = idx >> 5;       // t*4096 + b
    int t = rb >> 12;
    int b = rb & 4095;
    xpad[idx] = (c < INP) ? f2bfu(x[((size_t)b * TT + t) * INP + c]) : (u16)0;
}

// ---------------- fused gates + cell + projection kernel ----------------
// 1-D grid of 1024 blocks, 256 threads (4 waves). XCD-aware decode:
//   xcd = wgid & 7 owns nt in {2*xcd, 2*xcd+1}  -> W panel (1 MB) L2-resident.
// Block (mt, nt): gates[m0..m0+64][4 gates x 64 cols] -> LSTM cell -> h/c
// writes -> partial projection accumulated into out via atomicAdd.
__global__ __launch_bounds__(256, 4) void lstm_gates(
    const u16* __restrict__ h_in, u16* __restrict__ h_out,
    float* __restrict__ c_buf, const u16* __restrict__ whi,
    const u16* __restrict__ wihp, const float* __restrict__ bias,
    const u16* __restrict__ xpad, const u16* __restrict__ wlinp,
    const float* __restrict__ blin, float* __restrict__ outp,
    float* __restrict__ h_fin, int t, int is_last)
{
    __shared__ u16 sA[64 * 32];      //  4 KB  A tile (h rows)
    __shared__ u16 sB0[256 * 32];    // 16 KB  B tile (W rows); reused as h-tile
    __shared__ u16 sWl[INP * 64];    // 2.125 KB  W_lin slice [17][64]

    const int tid = threadIdx.x;
    const int lane = tid & 63;
    const int wv = tid >> 6;
    // XCD-aware block decode (bijective on 0..1023)
    const int wgid = blockIdx.x;
    const int xcd = wgid & 7;
    const int kk = wgid >> 3;              // 0..127
    const int nt = (xcd << 1) | (kk >> 6); // 0..15
    const int mt = kk & 63;                // 0..63
    const int m0 = mt * 64;
    const int r16 = lane & 15;
    const int s4 = lane >> 4;

    // staging mapping: thread -> (row srow, 16B slot sq)
    const int srow = tid >> 2;
    const int sq = tid & 3;
    const int a_dst = lds_off(srow, sq);

    // stage W_lin slice for this nt (once)
    for (int k = tid; k < INP * 64; k += 256)
        sWl[k] = wlinp[(k >> 6) * HH + nt * 64 + (k & 63)];

    f32x4 acc[4][4];
#pragma unroll
    for (int mf = 0; mf < 4; ++mf)
#pragma unroll
        for (int g = 0; g < 4; ++g) acc[mf][g] = (f32x4){0.f, 0.f, 0.f, 0.f};

    int aoff[4], boff[4];
#pragma unroll
    for (int mf = 0; mf < 4; ++mf) aoff[mf] = lds_off(mf * 16 + r16, s4);
#pragma unroll
    for (int g = 0; g < 4; ++g) boff[g] = lds_off(g * 64 + wv * 16 + r16, s4);

    // ---- x chunk (K padded 17 -> 32) ----
    {
        const u16* xsrc = xpad + ((size_t)t * BB + m0 + srow) * 32 + sq * 8;
        *(u32x4*)&sA[a_dst] = *(const u32x4*)xsrc;
#pragma unroll
        for (int rep = 0; rep < 4; ++rep) {
            int r = rep * 64 + srow;
            int wrow = (r >> 6) * HH + nt * 64 + (r & 63);
            *(u32x4*)&sB0[lds_off(r, sq)] = *(const u32x4*)(wihp + wrow * 32 + sq * 8);
        }
    }
    __syncthreads();
    {
        bf16x8 af[4];
#pragma unroll
        for (int mf = 0; mf < 4; ++mf)
            af[mf] = __builtin_bit_cast(bf16x8, *(const short8*)&sA[aoff[mf]]);
#pragma unroll
        for (int g = 0; g < 4; ++g) {
            bf16x8 bh = __builtin_bit_cast(bf16x8, *(const short8*)&sB0[boff[g]]);
#pragma unroll
            for (int mf = 0; mf < 4; ++mf)
                acc[mf][g] = __builtin_amdgcn_mfma_f32_16x16x32_bf16(af[mf], bh, acc[mf][g], 0, 0, 0);
        }
    }

    // ---- h chunks: K = 1024, BK = 32, single bf16 pass (reg-staged: the
    //      compiler hoists next-tile global loads above current MFMAs) ----
    for (int kc = 0; kc < HH; kc += 32) {
        __syncthreads();   // all waves done reading previous tiles
        *(u32x4*)&sA[a_dst] = *(const u32x4*)(h_in + (size_t)(m0 + srow) * HH + kc + sq * 8);
#pragma unroll
        for (int rep = 0; rep < 4; ++rep) {
            int r = rep * 64 + srow;
            int wrow = (r >> 6) * HH + nt * 64 + (r & 63);
            *(u32x4*)&sB0[lds_off(r, sq)] = *(const u32x4*)(whi + (size_t)wrow * HH + kc + sq * 8);
        }
        __syncthreads();   // tiles resident

        bf16x8 af[4];
#pragma unroll
        for (int mf = 0; mf < 4; ++mf)
            af[mf] = __builtin_bit_cast(bf16x8, *(const short8*)&sA[aoff[mf]]);
#pragma unroll
        for (int g = 0; g < 4; ++g) {
            bf16x8 bh = __builtin_bit_cast(bf16x8, *(const short8*)&sB0[boff[g]]);
#pragma unroll
            for (int mf = 0; mf < 4; ++mf)
                acc[mf][g] = __builtin_amdgcn_mfma_f32_16x16x32_bf16(af[mf], bh, acc[mf][g], 0, 0, 0);
        }
    }

    // ---- epilogue: LSTM cell; stash h-tile in LDS for fused projection ----
    __syncthreads();                 // done reading sB0 as B tile
    u16* hT = sB0;                   // reuse: hT[c*64 + ((r + 2c) & 63)] = h[r][c]
    const int n = nt * 64 + wv * 16 + r16;
    const int nl = wv * 16 + r16;    // local col 0..63
    const float bi = bias[n];
    const float bf_ = bias[HH + n];
    const float bg = bias[2 * HH + n];
    const float bo = bias[3 * HH + n];
#pragma unroll
    for (int mf = 0; mf < 4; ++mf) {
#pragma unroll
        for (int j = 0; j < 4; ++j) {
            int rl = mf * 16 + s4 * 4 + j;         // local row 0..63
            int brow = m0 + rl;
            float iv = fast_sigmoid(acc[mf][0][j] + bi);
            float fv = fast_sigmoid(acc[mf][1][j] + bf_);
            float gv = fast_tanh(acc[mf][2][j] + bg);
            float ov = fast_sigmoid(acc[mf][3][j] + bo);
            size_t ci = (size_t)brow * HH + n;
            float cold = c_buf[ci];
            float cnew = fv * cold + iv * gv;
            float hnew = ov * fast_tanh(cnew);
            c_buf[ci] = cnew;
            u16 hb = f2bfu(hnew);
            h_out[ci] = hb;
            hT[nl * 64 + ((rl + 2 * nl) & 63)] = hb;
            if (is_last) h_fin[ci] = hnew;
        }
    }
    __syncthreads();

    // ---- fused projection partial: out[b,i] += sum_c h[b,c]*Wlin[i,c] ----
    // thread -> row rl = tid&63; wave wv owns i in {wv, wv+4, ...}.
    {
        const int rl = tid & 63;
        float part[5] = {0.f, 0.f, 0.f, 0.f, 0.f};
        for (int c = 0; c < 64; ++c) {
            float hv = bfu2f(hT[c * 64 + ((rl + 2 * c) & 63)]);
#pragma unroll
            for (int k = 0; k < 5; ++k) {
                int i = wv + 4 * k;
                if (i < INP) part[k] += hv * bfu2f(sWl[i * 64 + c]);
            }
        }
        size_t ob = ((size_t)(m0 + rl) * TT + t) * INP;
#pragma unroll
        for (int k = 0; k < 5; ++k) {
            int i = wv + 4 * k;
            if (i < INP) {
                float v = part[k];
                if (nt == 0) v += blin[i];   // bias added exactly once
                atomicAdd(&outp[ob + i], v);
            }
        }
    }
}

// ---------------- launch ----------------
extern "C" void kernel_launch(void* const* d_in, const int* in_sizes, int n_in,
                              void* d_out, int out_size, void* d_ws, size_t ws_size,
                              hipStream_t stream)
{
    const float* x    = (const float*)d_in[0];
    const float* Wih  = (const float*)d_in[1];
    const float* Whh  = (const float*)d_in[2];
    const float* bih  = (const float*)d_in[3];
    const float* bhh  = (const float*)d_in[4];
    const float* Wlin = (const float*)d_in[5];
    const float* blin = (const float*)d_in[6];
    float* out = (float*)d_out;

    char* ws = (char*)d_ws;
    u16* hb0    = (u16*)(ws);                      //  8,388,608 B
    u16* hb1    = (u16*)(ws + 8388608);            //  8,388,608 B
    u16* xpad   = (u16*)(ws + 16777216);           //  4,980,736 B
    u16* whi    = (u16*)(ws + 21757952);           //  8,388,608 B
    u16* wihp   = (u16*)(ws + 30146560);           //    262,144 B
    u16* wlinp  = (u16*)(ws + 30408704);           //     34,816 B
    float* bias = (float*)(ws + 30443520);         //     16,384 B

    float* h_fin = out + (size_t)BB * TT * INP;    // h_fin region
    float* c_buf = h_fin + (size_t)BB * HH;        // c_fin region = c state

    hipMemsetAsync(out, 0, (size_t)BB * TT * INP * sizeof(float), stream);
    hipMemsetAsync(hb0, 0, (size_t)BB * HH * sizeof(u16), stream);
    hipMemsetAsync(c_buf, 0, (size_t)BB * HH * sizeof(float), stream);
    prep_w<<<2048, 256, 0, stream>>>(Whh, whi);
    prep_misc<<<512, 256, 0, stream>>>(Wih, bih, bhh, Wlin, wihp, bias, wlinp);
    prep_x<<<9728, 256, 0, stream>>>(x, xpad);

    for (int t = 0; t < TT; ++t) {
        const u16* hin = (t & 1) ? hb1 : hb0;
        u16* hout = (t & 1) ? hb0 : hb1;
        lstm_gates<<<1024, 256, 0, stream>>>(
            hin, hout, c_buf, whi, wihp, bias, xpad, wlinp, blin, out,
            h_fin, t, (t == TT - 1) ? 1 : 0);
    }
}